// Round 1
// baseline (174.283 us; speedup 1.0000x reference)
//
#include <hip/hip_runtime.h>
#include <cstdint>
#include <cstddef>

// ---------------------------------------------------------------------------
// RNN_No_FFNN: h_t = sigmoid(hidden@U_w.T + U_b + line@W_w.T + W_b)
//              pred = h_t@V_w.T + V_b ; out0 = segmented log_softmax(pred)
// B=8192, H=2048, D=104.  Outputs: [pred_logsoft (8192*104) | h_t (8192*2048)] f32.
// Strategy: bf16 MFMA for all GEMMs (threshold 8.8e-2 >> bf16 error ~6e-3).
// ---------------------------------------------------------------------------

typedef __bf16 bf16x8 __attribute__((ext_vector_type(8)));
typedef float  f32x4  __attribute__((ext_vector_type(4)));
typedef unsigned short ushort8 __attribute__((ext_vector_type(8)));
typedef float  float4v __attribute__((ext_vector_type(4)));

#define BB 8192
#define HH 2048
#define DD 104

static __device__ __forceinline__ unsigned short f2bf(float f) {
  unsigned u = __float_as_uint(f);
  unsigned r = (u + 0x7FFFu + ((u >> 16) & 1u)) >> 16;  // RNE
  return (unsigned short)r;
}

// async global->LDS, 16B per lane (guide §5: width=16 is the fast path)
#define GLD_LDS(g, l)                                                          \
  __builtin_amdgcn_global_load_lds(                                            \
      (__attribute__((address_space(1))) void*)(g),                            \
      (__attribute__((address_space(3))) void*)(l), 16, 0, 0)

// ---------------------------------------------------------------------------
// Conversion kernels
// ---------------------------------------------------------------------------

// hidden (16777216) then U_w (4194304), both f32 -> bf16, 8 elems/thread
__global__ __launch_bounds__(256) void conv_bf16_kernel(
    const float* __restrict__ hidden, const float* __restrict__ Uw,
    unsigned short* __restrict__ out_hidden, unsigned short* __restrict__ out_U) {
  long long i = ((long long)blockIdx.x * blockDim.x + threadIdx.x) * 8;
  const float* src; unsigned short* dst; long long off;
  if (i < (long long)BB * HH) { src = hidden; dst = out_hidden; off = i; }
  else { src = Uw; dst = out_U; off = i - (long long)BB * HH; }
  float4v a = *(const float4v*)(src + off);
  float4v b = *(const float4v*)(src + off + 4);
  ushort8 o;
  o[0]=f2bf(a[0]); o[1]=f2bf(a[1]); o[2]=f2bf(a[2]); o[3]=f2bf(a[3]);
  o[4]=f2bf(b[0]); o[5]=f2bf(b[1]); o[6]=f2bf(b[2]); o[7]=f2bf(b[3]);
  *(ushort8*)(dst + off) = o;
}

// line[8192,104]->line_pad[8192,128]; W_w[2048,104]->Ww_pad[2048,128];
// V_w[104,2048]->Vw_pad[128,2048] (zero padding; every element written each call)
__global__ __launch_bounds__(256) void pad_bf16_kernel(
    const float* __restrict__ line, const float* __restrict__ Ww,
    const float* __restrict__ Vw,
    unsigned short* __restrict__ line_pad, unsigned short* __restrict__ Ww_pad,
    unsigned short* __restrict__ Vw_pad) {
  int i = blockIdx.x * blockDim.x + threadIdx.x;
  const int N1 = BB * 128;          // 1048576
  const int N2 = N1 + HH * 128;     // +262144
  if (i < N1) {
    int r = i >> 7, c = i & 127;
    line_pad[i] = (c < DD) ? f2bf(line[r * DD + c]) : (unsigned short)0;
  } else if (i < N2) {
    int j = i - N1; int r = j >> 7, c = j & 127;
    Ww_pad[j] = (c < DD) ? f2bf(Ww[r * DD + c]) : (unsigned short)0;
  } else {
    int j = i - N2; int r = j >> 11, c = j & 2047;
    Vw_pad[j] = (r < DD) ? f2bf(Vw[r * 2048 + c]) : (unsigned short)0;
  }
}

// ---------------------------------------------------------------------------
// Shared MFMA tile step: C-quadrant fragments from LDS (B^T layout both sides)
// ---------------------------------------------------------------------------
template <int NM, int NN>
static __device__ __forceinline__ void mfma_step(
    const unsigned short* sA, const unsigned short* sB, int arow0, int brow0,
    int frow, int fk, f32x4 (&acc)[NM][NN]) {
  bf16x8 af[NM], bfr[NN];
#pragma unroll
  for (int m = 0; m < NM; ++m)
    af[m] = *(const bf16x8*)(sA + (arow0 + m * 16 + frow) * 32 + fk);
#pragma unroll
  for (int n = 0; n < NN; ++n)
    bfr[n] = *(const bf16x8*)(sB + (brow0 + n * 16 + frow) * 32 + fk);
#pragma unroll
  for (int m = 0; m < NM; ++m)
#pragma unroll
    for (int n = 0; n < NN; ++n)
      acc[m][n] = __builtin_amdgcn_mfma_f32_16x16x32_bf16(af[m], bfr[n], acc[m][n], 0, 0, 0);
}

// ---------------------------------------------------------------------------
// GEMM1: h_pre = hidden@U_w.T (K=2048) + line_pad@Ww_pad.T (K=128, zero-padded)
//        h_t = sigmoid(h_pre + U_b + W_b); write f32 h_t (d_out) + bf16 h_t (ws)
// 128x128 tile, 4 waves (2x2), 64x64/wave, BK=32, m97 structure.
// ---------------------------------------------------------------------------
__global__ __launch_bounds__(256, 2) void gemm1_kernel(
    const unsigned short* __restrict__ A,   // hidden bf16 [8192][2048]
    const unsigned short* __restrict__ Bm,  // U_w bf16 [2048][2048]
    const unsigned short* __restrict__ A2,  // line_pad [8192][128]
    const unsigned short* __restrict__ B2,  // Ww_pad [2048][128]
    const float* __restrict__ Ub, const float* __restrict__ Wb,
    float* __restrict__ outH,               // f32 h_t
    unsigned short* __restrict__ outHbf) {  // bf16 h_t
  __shared__ unsigned short sA[128 * 32];
  __shared__ unsigned short sB[128 * 32];
  const int t = threadIdx.x;
  const int l = t & 63;
  const int wid = t >> 6, wr = wid >> 1, wc = wid & 1;
  const int bt = blockIdx.x;
  const int brow = (bt >> 4) * 128;  // 64 M-tiles
  const int bcol = (bt & 15) * 128;  // 16 N-tiles
  const int srow = t >> 2, scg = t & 3;
  const int frow = l & 15, fk = (l >> 4) * 8;

  const unsigned short* gA = A + (size_t)(brow + srow) * HH + scg * 8;
  const unsigned short* gB = Bm + (size_t)(bcol + srow) * HH + scg * 8;
  unsigned short* lA = sA + t * 8;  // byte offset t*16: linear, matches lane order
  unsigned short* lB = sB + t * 8;

  f32x4 acc[4][4] = {};

  // Phase 1: K=2048 over hidden/U_w
  for (int ks = 0; ks < 64; ++ks) {
    __syncthreads();
    GLD_LDS(gA, lA);
    GLD_LDS(gA + 64 * HH, lA + 64 * 32);
    GLD_LDS(gB, lB);
    GLD_LDS(gB + 64 * HH, lB + 64 * 32);
    gA += 32; gB += 32;
    __syncthreads();
    mfma_step<4, 4>(sA, sB, wr * 64, wc * 64, frow, fk, acc);
  }
  // Phase 2: K=128 (line@W_w.T, zero-padded cols 104..127)
  const unsigned short* gA2 = A2 + (size_t)(brow + srow) * 128 + scg * 8;
  const unsigned short* gB2 = B2 + (size_t)(bcol + srow) * 128 + scg * 8;
  for (int ks = 0; ks < 4; ++ks) {
    __syncthreads();
    GLD_LDS(gA2, lA);
    GLD_LDS(gA2 + 64 * 128, lA + 64 * 32);
    GLD_LDS(gB2, lB);
    GLD_LDS(gB2 + 64 * 128, lB + 64 * 32);
    gA2 += 32; gB2 += 32;
    __syncthreads();
    mfma_step<4, 4>(sA, sB, wr * 64, wc * 64, frow, fk, acc);
  }

  // Epilogue: +bias, sigmoid, dual write (C/D layout: col=l&15, row=(l>>4)*4+j)
#pragma unroll
  for (int n = 0; n < 4; ++n) {
    const int col = bcol + wc * 64 + n * 16 + frow;
    const float bias = Ub[col] + Wb[col];
#pragma unroll
    for (int m = 0; m < 4; ++m) {
      const int row0 = brow + wr * 64 + m * 16 + (l >> 4) * 4;
#pragma unroll
      for (int j = 0; j < 4; ++j) {
        const float v = acc[m][n][j] + bias;
        const float h = 1.0f / (1.0f + __expf(-v));
        const size_t idx = (size_t)(row0 + j) * HH + col;
        outH[idx] = h;
        outHbf[idx] = f2bf(h);
      }
    }
  }
}

// ---------------------------------------------------------------------------
// GEMM2: pred = h_t@V_w.T + V_b (M=8192,N=128pad,K=2048) + fused segmented
// log-softmax. 64-row tile -> 128 blocks. Waves 2x2: 32 rows x 64 cols each.
// ---------------------------------------------------------------------------
__global__ __launch_bounds__(256, 2) void gemm2_kernel(
    const unsigned short* __restrict__ A,   // h_t bf16 [8192][2048]
    const unsigned short* __restrict__ Bm,  // Vw_pad [128][2048]
    const float* __restrict__ Vb,
    float* __restrict__ outLS) {            // [8192][104] f32
  __shared__ unsigned short sA[64 * 32];
  __shared__ unsigned short sB[128 * 32];
  __shared__ float pred[64 * 105];          // stride 105: conflict-free serial phase
  const int t = threadIdx.x;
  const int l = t & 63;
  const int wid = t >> 6, wr = wid >> 1, wc = wid & 1;
  const int brow = blockIdx.x * 64;
  const int srow = t >> 2, scg = t & 3;
  const int frow = l & 15, fk = (l >> 4) * 8;

  const unsigned short* gA = A + (size_t)(brow + srow) * HH + scg * 8;
  const unsigned short* gB = Bm + (size_t)srow * HH + scg * 8;
  unsigned short* lA = sA + t * 8;
  unsigned short* lB = sB + t * 8;

  f32x4 acc[2][4] = {};
  for (int ks = 0; ks < 64; ++ks) {
    __syncthreads();
    GLD_LDS(gA, lA);             // A: 64 rows x 32 -> exactly one 256-thread issue
    GLD_LDS(gB, lB);
    GLD_LDS(gB + 64 * HH, lB + 64 * 32);
    gA += 32; gB += 32;
    __syncthreads();
    mfma_step<2, 4>(sA, sB, wr * 32, wc * 64, frow, fk, acc);
  }

  // write pred tile (+V_b) to LDS; cols >= 104 are pad, skip
#pragma unroll
  for (int n = 0; n < 4; ++n) {
    const int col = wc * 64 + n * 16 + frow;
    if (col < DD) {
      const float vb = Vb[col];
#pragma unroll
      for (int m = 0; m < 2; ++m) {
        const int r0 = wr * 32 + m * 16 + (l >> 4) * 4;
#pragma unroll
        for (int j = 0; j < 4; ++j)
          pred[(r0 + j) * 105 + col] = acc[m][n][j] + vb;
      }
    }
  }
  __syncthreads();

  // per-row segmented log-softmax: one thread per row
  if (t < 64) {
    const int segb[11] = {0, 13, 26, 39, 48, 52, 65, 78, 91, 100, 104};
    const float* p = pred + t * 105;
    float* o = outLS + (size_t)(brow + t) * DD;
    for (int s = 0; s < 10; ++s) {
      const int a = segb[s], b = segb[s + 1];
      float mx = -3.0e38f;
      for (int c = a; c < b; ++c) mx = fmaxf(mx, p[c]);
      float sum = 0.0f;
      for (int c = a; c < b; ++c) sum += __expf(p[c] - mx);
      const float ls = __logf(sum) + mx;
      for (int c = a; c < b; ++c) o[c] = p[c] - ls;
    }
  }
}

// ---------------------------------------------------------------------------
// Launch
// ---------------------------------------------------------------------------
extern "C" void kernel_launch(void* const* d_in, const int* in_sizes, int n_in,
                              void* d_out, int out_size, void* d_ws, size_t ws_size,
                              hipStream_t stream) {
  (void)in_sizes; (void)n_in; (void)out_size; (void)ws_size;
  const float* line   = (const float*)d_in[0];
  const float* hidden = (const float*)d_in[1];
  const float* Uw     = (const float*)d_in[2];
  const float* Ub     = (const float*)d_in[3];
  const float* Ww     = (const float*)d_in[4];
  const float* Wb     = (const float*)d_in[5];
  const float* Vw     = (const float*)d_in[6];
  const float* Vb     = (const float*)d_in[7];

  char* ws = (char*)d_ws;
  // ws layout (bytes), total ~78.6 MB
  unsigned short* hid_bf  = (unsigned short*)(ws);              // 33,554,432
  unsigned short* U_bf    = (unsigned short*)(ws + 33554432);   //  8,388,608
  unsigned short* line_bf = (unsigned short*)(ws + 41943040);   //  2,097,152
  unsigned short* Ww_bf   = (unsigned short*)(ws + 44040192);   //    524,288
  unsigned short* Vw_bf   = (unsigned short*)(ws + 44564480);   //    524,288
  unsigned short* ht_bf   = (unsigned short*)(ws + 45088768);   // 33,554,432

  float* outLS = (float*)d_out;                 // [8192][104]
  float* outH  = (float*)d_out + (size_t)BB * DD;  // [8192][2048]

  // (16777216 + 4194304)/8/256 = 10240 blocks, exact cover
  conv_bf16_kernel<<<10240, 256, 0, stream>>>(hidden, Uw, hid_bf, U_bf);
  // (1048576 + 262144 + 262144)/256 = 6144 blocks, exact cover
  pad_bf16_kernel<<<6144, 256, 0, stream>>>(line, Ww, Vw, line_bf, Ww_bf, Vw_bf);
  gemm1_kernel<<<1024, 256, 0, stream>>>(hid_bf, U_bf, line_bf, Ww_bf, Ub, Wb,
                                         outH, ht_bf);
  gemm2_kernel<<<128, 256, 0, stream>>>(ht_bf, Vw_bf, Vb, outLS);
}

// Round 2
// 135.797 us; speedup vs baseline: 1.2834x; 1.2834x over previous
//
#include <hip/hip_runtime.h>
#include <cstdint>
#include <cstddef>

// ---------------------------------------------------------------------------
// RNN_No_FFNN: h_t = sigmoid(hidden@U_w.T + U_b + line@W_w.T + W_b)
//              pred = h_t@V_w.T + V_b ; out0 = segmented log_softmax(pred)
// B=8192, H=2048, D=104.  Outputs: [pred_logsoft (8192*104) | h_t (8192*2048)] f32.
// gemm1: 256x256 tile, 8-phase schedule, BK=32 x 4 LDS buffers, counted vmcnt,
//        T2 XOR swizzle, setprio around MFMA clusters.
// ---------------------------------------------------------------------------

typedef __bf16 bf16x8 __attribute__((ext_vector_type(8)));
typedef float  f32x4  __attribute__((ext_vector_type(4)));
typedef unsigned short ushort8 __attribute__((ext_vector_type(8)));
typedef float  float4v __attribute__((ext_vector_type(4)));

#define BB 8192
#define HH 2048
#define DD 104

static __device__ __forceinline__ unsigned short f2bf(float f) {
  unsigned u = __float_as_uint(f);
  unsigned r = (u + 0x7FFFu + ((u >> 16) & 1u)) >> 16;  // RNE
  return (unsigned short)r;
}

// async global->LDS, 16B per lane
#define GLD_LDS(g, l)                                                          \
  __builtin_amdgcn_global_load_lds(                                            \
      (__attribute__((address_space(1))) void*)(g),                            \
      (__attribute__((address_space(3))) void*)(l), 16, 0, 0)

// ---------------------------------------------------------------------------
// Conversion kernels
// ---------------------------------------------------------------------------
__global__ __launch_bounds__(256) void conv_bf16_kernel(
    const float* __restrict__ hidden, const float* __restrict__ Uw,
    unsigned short* __restrict__ out_hidden, unsigned short* __restrict__ out_U) {
  long long i = ((long long)blockIdx.x * blockDim.x + threadIdx.x) * 8;
  const float* src; unsigned short* dst; long long off;
  if (i < (long long)BB * HH) { src = hidden; dst = out_hidden; off = i; }
  else { src = Uw; dst = out_U; off = i - (long long)BB * HH; }
  float4v a = *(const float4v*)(src + off);
  float4v b = *(const float4v*)(src + off + 4);
  ushort8 o;
  o[0]=f2bf(a[0]); o[1]=f2bf(a[1]); o[2]=f2bf(a[2]); o[3]=f2bf(a[3]);
  o[4]=f2bf(b[0]); o[5]=f2bf(b[1]); o[6]=f2bf(b[2]); o[7]=f2bf(b[3]);
  *(ushort8*)(dst + off) = o;
}

__global__ __launch_bounds__(256) void pad_bf16_kernel(
    const float* __restrict__ line, const float* __restrict__ Ww,
    const float* __restrict__ Vw,
    unsigned short* __restrict__ line_pad, unsigned short* __restrict__ Ww_pad,
    unsigned short* __restrict__ Vw_pad) {
  int i = blockIdx.x * blockDim.x + threadIdx.x;
  const int N1 = BB * 128;          // 1048576
  const int N2 = N1 + HH * 128;     // +262144
  if (i < N1) {
    int r = i >> 7, c = i & 127;
    line_pad[i] = (c < DD) ? f2bf(line[r * DD + c]) : (unsigned short)0;
  } else if (i < N2) {
    int j = i - N1; int r = j >> 7, c = j & 127;
    Ww_pad[j] = (c < DD) ? f2bf(Ww[r * DD + c]) : (unsigned short)0;
  } else {
    int j = i - N2; int r = j >> 11, c = j & 2047;
    Vw_pad[j] = (r < DD) ? f2bf(Vw[r * 2048 + c]) : (unsigned short)0;
  }
}

// ---------------------------------------------------------------------------
// GEMM1 8-phase: one K-tile (BK=32) = 2 phases. 4 LDS buffers.
// LDS tile layout [256 rows][32 cols] bf16, 16B slots XOR-swizzled:
//   LDS[row][slot] holds global[row][slot ^ ((row>>1)&3)]
// write side: global_load_lds dest linear, SOURCE address pre-swizzled;
// read side: ds_read at slot ^ ((frow>>1)&3). 2-way bank access (free).
// ---------------------------------------------------------------------------
template <int J>
static __device__ __forceinline__ void ktile(
    int it, unsigned short* smem, int aoff, int boff,
    const unsigned short* pAh, const unsigned short* pAl,
    const unsigned short* pBu, const unsigned short* pBw,
    unsigned short* dA, unsigned short* dB, f32x4 (&acc)[8][4]) {
  constexpr int BUF  = J;
  constexpr int BUFS = (J + 3) & 3;
  int kbs = it * 128 + J * 32 + 96;      // stage target = tile T+3
  if (kbs >= 2176) kbs = 2144;           // tail: dummy re-stage into dead buffer
  const unsigned short* ar = smem + BUF * 16384 + aoff;
  const unsigned short* br = smem + BUF * 16384 + boff;
  bf16x8 av[4], bv[4];

  // ---- phase 0: Mh=0 ----
#pragma unroll
  for (int mi = 0; mi < 4; ++mi) av[mi] = *(const bf16x8*)(ar + mi * 512);
#pragma unroll
  for (int n = 0; n < 4; ++n) bv[n] = *(const bf16x8*)(br + n * 512);
  if (kbs < 2048) {
    GLD_LDS(pAh + kbs, dA + BUFS * 16384);
    GLD_LDS(pAh + kbs + 128 * 2048, dA + BUFS * 16384 + 4096);
  } else {
    GLD_LDS(pAl + (kbs - 2048), dA + BUFS * 16384);
    GLD_LDS(pAl + (kbs - 2048) + 128 * 128, dA + BUFS * 16384 + 4096);
  }
  __builtin_amdgcn_s_barrier();
  asm volatile("s_waitcnt lgkmcnt(0)" ::: "memory");
  __builtin_amdgcn_s_setprio(1);
#pragma unroll
  for (int mi = 0; mi < 4; ++mi)
#pragma unroll
    for (int n = 0; n < 4; ++n)
      acc[mi][n] = __builtin_amdgcn_mfma_f32_16x16x32_bf16(av[mi], bv[n], acc[mi][n], 0, 0, 0);
  __builtin_amdgcn_s_setprio(0);
  __builtin_amdgcn_s_barrier();

  // ---- phase 1: Mh=1 (reuse bv) ----
#pragma unroll
  for (int mi = 0; mi < 4; ++mi) av[mi] = *(const bf16x8*)(ar + 2048 + mi * 512);
  if (kbs < 2048) {
    GLD_LDS(pBu + kbs, dB + BUFS * 16384);
    GLD_LDS(pBu + kbs + 128 * 2048, dB + BUFS * 16384 + 4096);
  } else {
    GLD_LDS(pBw + (kbs - 2048), dB + BUFS * 16384);
    GLD_LDS(pBw + (kbs - 2048) + 128 * 128, dB + BUFS * 16384 + 4096);
  }
  __builtin_amdgcn_s_barrier();
  asm volatile("s_waitcnt lgkmcnt(0)" ::: "memory");
  __builtin_amdgcn_s_setprio(1);
#pragma unroll
  for (int mi = 0; mi < 4; ++mi)
#pragma unroll
    for (int n = 0; n < 4; ++n)
      acc[4 + mi][n] = __builtin_amdgcn_mfma_f32_16x16x32_bf16(av[mi], bv[n], acc[4 + mi][n], 0, 0, 0);
  __builtin_amdgcn_s_setprio(0);
  // counted wait: forces tile T+1's 4 loads landed; T+2,T+3 stay in flight
  asm volatile("s_waitcnt vmcnt(8)" ::: "memory");
  __builtin_amdgcn_s_barrier();
}

__global__ __launch_bounds__(512, 2) void gemm1_kernel(
    const unsigned short* __restrict__ Ahid,   // [8192][2048] bf16
    const unsigned short* __restrict__ Aline,  // [8192][128]  bf16 (zero-pad)
    const unsigned short* __restrict__ BU,     // [2048][2048] bf16
    const unsigned short* __restrict__ BW,     // [2048][128]  bf16 (zero-pad)
    const float* __restrict__ Ub, const float* __restrict__ Wb,
    float* __restrict__ outH, unsigned short* __restrict__ outHbf) {
  __shared__ unsigned short smem[65536];       // 4 bufs x (A 8192 + B 8192) elems
  const int t = threadIdx.x;
  const int l = t & 63;
  const int wid = t >> 6;
  const int wr = wid >> 2, wc = wid & 3;       // 2 x 4 waves
  // XCD swizzle: 256 wgs, 8 XCDs, chunk 32
  const int bid = blockIdx.x;
  const int wg = (bid & 7) * 32 + (bid >> 3);
  const int brow = (wg >> 3) * 256;            // 32 M tiles
  const int bcol = (wg & 7) * 256;             // 8 N tiles

  const int frow = l & 15;
  const int slot_r = (l >> 4) ^ ((frow >> 1) & 3);
  const int lrow = t >> 2;
  const int sl8 = (((t & 3) ^ ((t >> 3) & 3)) * 8);  // pre-swizzled source slot

  const unsigned short* pAh = Ahid + (size_t)(brow + lrow) * 2048 + sl8;
  const unsigned short* pAl = Aline + (size_t)(brow + lrow) * 128 + sl8;
  const unsigned short* pBu = BU + (size_t)(bcol + lrow) * 2048 + sl8;
  const unsigned short* pBw = BW + (size_t)(bcol + lrow) * 128 + sl8;

  unsigned short* dA = smem + t * 8;           // + buf*16384 (+4096 for half 1)
  unsigned short* dB = smem + 8192 + t * 8;

  const int aoff = (wr * 128 + frow) * 32 + slot_r * 8;
  const int boff = 8192 + (wc * 64 + frow) * 32 + slot_r * 8;

  f32x4 acc[8][4] = {};

  // prologue: stage tiles 0,1,2 into bufs 0,1,2 (12 issues/wave)
#pragma unroll
  for (int p = 0; p < 3; ++p) {
    GLD_LDS(pAh + p * 32, dA + p * 16384);
    GLD_LDS(pAh + p * 32 + 128 * 2048, dA + p * 16384 + 4096);
    GLD_LDS(pBu + p * 32, dB + p * 16384);
    GLD_LDS(pBu + p * 32 + 128 * 2048, dB + p * 16384 + 4096);
  }
  asm volatile("s_waitcnt vmcnt(8)" ::: "memory");  // tile 0 landed
  __builtin_amdgcn_s_barrier();

  // 68 K-tiles of 32 (K = 2048 + 128 concat), 17 x 4
  for (int it = 0; it < 17; ++it) {
    ktile<0>(it, smem, aoff, boff, pAh, pAl, pBu, pBw, dA, dB, acc);
    ktile<1>(it, smem, aoff, boff, pAh, pAl, pBu, pBw, dA, dB, acc);
    ktile<2>(it, smem, aoff, boff, pAh, pAl, pBu, pBw, dA, dB, acc);
    ktile<3>(it, smem, aoff, boff, pAh, pAl, pBu, pBw, dA, dB, acc);
  }
  asm volatile("s_waitcnt vmcnt(0)" ::: "memory");  // drain tail dummy stages

  // epilogue: +bias, sigmoid, dual write
  const int erow = (l >> 4) * 4;
#pragma unroll
  for (int n = 0; n < 4; ++n) {
    const int col = bcol + wc * 64 + n * 16 + frow;
    const float bias = Ub[col] + Wb[col];
#pragma unroll
    for (int m = 0; m < 8; ++m) {
      const int r0 = brow + wr * 128 + m * 16 + erow;
#pragma unroll
      for (int jj = 0; jj < 4; ++jj) {
        const float v = acc[m][n][jj] + bias;
        const float h = 1.0f / (1.0f + __expf(-v));
        const size_t idx = (size_t)(r0 + jj) * HH + col;
        outH[idx] = h;
        outHbf[idx] = f2bf(h);
      }
    }
  }
}

// ---------------------------------------------------------------------------
// GEMM2 (unchanged): pred = h_t@V_w.T + V_b + fused segmented log-softmax
// ---------------------------------------------------------------------------
template <int NM, int NN>
static __device__ __forceinline__ void mfma_step(
    const unsigned short* sA, const unsigned short* sB, int arow0, int brow0,
    int frow, int fk, f32x4 (&acc)[NM][NN]) {
  bf16x8 af[NM], bfr[NN];
#pragma unroll
  for (int m = 0; m < NM; ++m)
    af[m] = *(const bf16x8*)(sA + (arow0 + m * 16 + frow) * 32 + fk);
#pragma unroll
  for (int n = 0; n < NN; ++n)
    bfr[n] = *(const bf16x8*)(sB + (brow0 + n * 16 + frow) * 32 + fk);
#pragma unroll
  for (int m = 0; m < NM; ++m)
#pragma unroll
    for (int n = 0; n < NN; ++n)
      acc[m][n] = __builtin_amdgcn_mfma_f32_16x16x32_bf16(af[m], bfr[n], acc[m][n], 0, 0, 0);
}

__global__ __launch_bounds__(256, 2) void gemm2_kernel(
    const unsigned short* __restrict__ A,   // h_t bf16 [8192][2048]
    const unsigned short* __restrict__ Bm,  // Vw_pad [128][2048]
    const float* __restrict__ Vb,
    float* __restrict__ outLS) {            // [8192][104] f32
  __shared__ unsigned short sA[64 * 32];
  __shared__ unsigned short sB[128 * 32];
  __shared__ float pred[64 * 105];
  const int t = threadIdx.x;
  const int l = t & 63;
  const int wid = t >> 6, wr = wid >> 1, wc = wid & 1;
  const int brow = blockIdx.x * 64;
  const int srow = t >> 2, scg = t & 3;
  const int frow = l & 15, fk = (l >> 4) * 8;

  const unsigned short* gA = A + (size_t)(brow + srow) * HH + scg * 8;
  const unsigned short* gB = Bm + (size_t)srow * HH + scg * 8;
  unsigned short* lA = sA + t * 8;
  unsigned short* lB = sB + t * 8;

  f32x4 acc[2][4] = {};
  for (int ks = 0; ks < 64; ++ks) {
    __syncthreads();
    GLD_LDS(gA, lA);
    GLD_LDS(gB, lB);
    GLD_LDS(gB + 64 * HH, lB + 64 * 32);
    gA += 32; gB += 32;
    __syncthreads();
    mfma_step<2, 4>(sA, sB, wr * 32, wc * 64, frow, fk, acc);
  }

#pragma unroll
  for (int n = 0; n < 4; ++n) {
    const int col = wc * 64 + n * 16 + frow;
    if (col < DD) {
      const float vb = Vb[col];
#pragma unroll
      for (int m = 0; m < 2; ++m) {
        const int r0 = wr * 32 + m * 16 + (l >> 4) * 4;
#pragma unroll
        for (int j = 0; j < 4; ++j)
          pred[(r0 + j) * 105 + col] = acc[m][n][j] + vb;
      }
    }
  }
  __syncthreads();

  if (t < 64) {
    const int segb[11] = {0, 13, 26, 39, 48, 52, 65, 78, 91, 100, 104};
    const float* p = pred + t * 105;
    float* o = outLS + (size_t)(brow + t) * DD;
    for (int s = 0; s < 10; ++s) {
      const int a = segb[s], b = segb[s + 1];
      float mx = -3.0e38f;
      for (int c = a; c < b; ++c) mx = fmaxf(mx, p[c]);
      float sum = 0.0f;
      for (int c = a; c < b; ++c) sum += __expf(p[c] - mx);
      const float ls = __logf(sum) + mx;
      for (int c = a; c < b; ++c) o[c] = p[c] - ls;
    }
  }
}

// ---------------------------------------------------------------------------
// Launch
// ---------------------------------------------------------------------------
extern "C" void kernel_launch(void* const* d_in, const int* in_sizes, int n_in,
                              void* d_out, int out_size, void* d_ws, size_t ws_size,
                              hipStream_t stream) {
  (void)in_sizes; (void)n_in; (void)out_size; (void)ws_size;
  const float* line   = (const float*)d_in[0];
  const float* hidden = (const float*)d_in[1];
  const float* Uw     = (const float*)d_in[2];
  const float* Ub     = (const float*)d_in[3];
  const float* Ww     = (const float*)d_in[4];
  const float* Wb     = (const float*)d_in[5];
  const float* Vw     = (const float*)d_in[6];
  const float* Vb     = (const float*)d_in[7];

  char* ws = (char*)d_ws;
  unsigned short* hid_bf  = (unsigned short*)(ws);              // 33,554,432 B
  unsigned short* U_bf    = (unsigned short*)(ws + 33554432);   //  8,388,608
  unsigned short* line_bf = (unsigned short*)(ws + 41943040);   //  2,097,152
  unsigned short* Ww_bf   = (unsigned short*)(ws + 44040192);   //    524,288
  unsigned short* Vw_bf   = (unsigned short*)(ws + 44564480);   //    524,288
  unsigned short* ht_bf   = (unsigned short*)(ws + 45088768);   // 33,554,432

  float* outLS = (float*)d_out;                    // [8192][104]
  float* outH  = (float*)d_out + (size_t)BB * DD;  // [8192][2048]

  conv_bf16_kernel<<<10240, 256, 0, stream>>>(hidden, Uw, hid_bf, U_bf);
  pad_bf16_kernel<<<6144, 256, 0, stream>>>(line, Ww, Vw, line_bf, Ww_bf, Vw_bf);
  gemm1_kernel<<<256, 512, 0, stream>>>(hid_bf, line_bf, U_bf, Ww_bf, Ub, Wb,
                                        outH, ht_bf);
  gemm2_kernel<<<128, 256, 0, stream>>>(ht_bf, Vw_bf, Vb, outLS);
}